// Round 1
// baseline (775.137 us; speedup 1.0000x reference)
//
#include <hip/hip_runtime.h>
#include <math.h>

#define BB 8
#define C 64
#define H 128
#define W 128
#define KO 18   // offset conv out channels (2*3*3)
#define NG 8    // groups
#define CPG 8   // channels per group
#define KK 9    // kernel taps

// ---------------------------------------------------------------------------
// Kernel 1: fused offset-conv (64->18) + PReLU  and  atten-conv (64->64)
//           + softmax over W.  Block = one (b,h) row, 128 threads = w.
// ---------------------------------------------------------------------------
__global__ __launch_bounds__(128)
void conv_offset_atten_kernel(const float* __restrict__ x,
                              const float* __restrict__ offw,   // [18][64][3][3]
                              const float* __restrict__ offb,   // [18]
                              const float* __restrict__ prelu_a,// [1]
                              const float* __restrict__ convw,  // [64][64][3][3]
                              float* __restrict__ ws_offset,    // [B][18][H][W]
                              float* __restrict__ ws_atten)     // [B][64][H][W]
{
    __shared__ float tile[3 * 130];        // rows h-1..h+1, cols -1..128
    __shared__ float smem[64 * 129];       // atten logits, padded stride
    __shared__ float red_m[64], red_s[64];

    const int bid = blockIdx.x;
    const int b = bid >> 7;
    const int h = bid & 127;
    const int w = threadIdx.x;             // 0..127

    float accOff[KO];
    float accAtt[C];
#pragma unroll
    for (int i = 0; i < KO; i++) accOff[i] = offb[i];
#pragma unroll
    for (int i = 0; i < C; i++) accAtt[i] = 0.f;

    const float* xb = x + (size_t)b * C * H * W;

    for (int ci = 0; ci < C; ci++) {
        __syncthreads();
        // stage 3x130 halo tile for this input channel
        for (int idx = threadIdx.x; idx < 3 * 130; idx += 128) {
            int r = idx / 130;
            int c = idx - r * 130 - 1;     // -1..128
            int y = h - 1 + r;
            float v = 0.f;
            if (y >= 0 && y < H && c >= 0 && c < W)
                v = xb[ci * H * W + y * W + c];
            tile[idx] = v;
        }
        __syncthreads();

        float xv[9];
#pragma unroll
        for (int r = 0; r < 3; r++)
#pragma unroll
            for (int c = 0; c < 3; c++)
                xv[r * 3 + c] = tile[r * 130 + w + c];

        const float* ow = offw + ci * 9;   // + co*(64*9) later
#pragma unroll
        for (int co = 0; co < KO; co++) {
            const float* wp = ow + co * (C * 9);
#pragma unroll
            for (int t = 0; t < 9; t++) accOff[co] = fmaf(xv[t], wp[t], accOff[co]);
        }
        const float* cw = convw + ci * 9;
#pragma unroll
        for (int co = 0; co < C; co++) {
            const float* wp = cw + co * (C * 9);
#pragma unroll
            for (int t = 0; t < 9; t++) accAtt[co] = fmaf(xv[t], wp[t], accAtt[co]);
        }
    }

    // ---- offsets: PReLU then store ----
    const float a = prelu_a[0];
    float* offo = ws_offset + ((size_t)b * KO) * H * W + h * W + w;
#pragma unroll
    for (int co = 0; co < KO; co++) {
        float v = accOff[co];
        v = (v >= 0.f) ? v : a * v;
        offo[co * H * W] = v;
    }

    // ---- softmax over W per (co) row ----
    __syncthreads();
#pragma unroll
    for (int co = 0; co < C; co++) smem[co * 129 + w] = accAtt[co];
    __syncthreads();
    if (threadIdx.x < 64) {
        const int co = threadIdx.x;
        float m = -INFINITY;
        for (int i = 0; i < W; i++) m = fmaxf(m, smem[co * 129 + i]);
        float s = 0.f;
        for (int i = 0; i < W; i++) s += __expf(smem[co * 129 + i] - m);
        red_m[co] = m;
        red_s[co] = 1.f / s;
    }
    __syncthreads();
    float* atto = ws_atten + ((size_t)b * C) * H * W + h * W + w;
#pragma unroll
    for (int co = 0; co < C; co++) {
        float v = __expf(smem[co * 129 + w] - red_m[co]) * red_s[co];
        atto[co * H * W] = v;
    }
}

// ---------------------------------------------------------------------------
// Kernel 2: deformable conv (groups=8) + bias, then out = atten*feat + x.
//           One thread per output pixel (all 64 cout in registers).
//           Lanes are consecutive w so gathers cluster into few cache lines.
// ---------------------------------------------------------------------------
__global__ __launch_bounds__(256)
void deform_kernel(const float* __restrict__ x,
                   const float* __restrict__ dw,        // [64][8][3][3]
                   const float* __restrict__ db,        // [64]
                   const float* __restrict__ ws_offset, // [B][18][H][W]
                   const float* __restrict__ ws_atten,  // [B][64][H][W]
                   float* __restrict__ out)             // [B][64][H][W]
{
    __shared__ float wlds[9 * 512];   // [k][g][il][ol]

    for (int i = threadIdx.x; i < 9 * 512; i += 256) {
        int ol = i & 7;
        int il = (i >> 3) & 7;
        int g  = (i >> 6) & 7;
        int k  = i >> 9;
        wlds[i] = dw[((g * 8 + ol) * 8 + il) * 9 + k];
    }
    __syncthreads();

    const int pid = blockIdx.x * 256 + threadIdx.x;   // 0 .. B*H*W-1
    const int w = pid & 127;
    const int h = (pid >> 7) & 127;
    const int b = pid >> 14;

    const float* xb = x + (size_t)b * C * H * W;
    const float* offp = ws_offset + (size_t)b * KO * H * W + h * W + w;

    float acc[C];
#pragma unroll
    for (int i = 0; i < C; i++) acc[i] = 0.f;

    for (int k = 0; k < KK; k++) {
        const int ky = k / 3;
        const int kx = k - ky * 3;
        const float dy = offp[(2 * k) * H * W];
        const float dx = offp[(2 * k + 1) * H * W];
        const float ys = (float)(h - 1 + ky) + dy;
        const float xs = (float)(w - 1 + kx) + dx;
        const float y0f = floorf(ys), x0f = floorf(xs);
        const int y0 = (int)y0f, x0 = (int)x0f;
        const float fy = ys - y0f, fx = xs - x0f;
        float w00 = (1.f - fy) * (1.f - fx);
        float w01 = (1.f - fy) * fx;
        float w10 = fy * (1.f - fx);
        float w11 = fy * fx;
        const bool vy0 = (y0 >= 0) & (y0 < H);
        const bool vy1 = (y0 + 1 >= 0) & (y0 + 1 < H);
        const bool vx0 = (x0 >= 0) & (x0 < W);
        const bool vx1 = (x0 + 1 >= 0) & (x0 + 1 < W);
        w00 = (vy0 && vx0) ? w00 : 0.f;
        w01 = (vy0 && vx1) ? w01 : 0.f;
        w10 = (vy1 && vx0) ? w10 : 0.f;
        w11 = (vy1 && vx1) ? w11 : 0.f;
        const int yc0 = min(max(y0, 0), H - 1);
        const int yc1 = min(max(y0 + 1, 0), H - 1);
        const int xc0 = min(max(x0, 0), W - 1);
        const int xc1 = min(max(x0 + 1, 0), W - 1);
        const int o00 = yc0 * W + xc0, o01 = yc0 * W + xc1;
        const int o10 = yc1 * W + xc0, o11 = yc1 * W + xc1;

        const float* wk = wlds + k * 512;
#pragma unroll
        for (int g = 0; g < NG; g++) {
#pragma unroll
            for (int il = 0; il < CPG; il++) {
                const float* xp = xb + (g * CPG + il) * H * W;
                const float p = w00 * xp[o00] + w01 * xp[o01]
                              + w10 * xp[o10] + w11 * xp[o11];
                const float* wp = wk + g * 64 + il * 8;
#pragma unroll
                for (int ol = 0; ol < CPG; ol++)
                    acc[g * CPG + ol] = fmaf(p, wp[ol], acc[g * CPG + ol]);
            }
        }
    }

    const float* attp = ws_atten + (size_t)b * C * H * W + h * W + w;
    const float* xr = xb + h * W + w;
    float* op = out + (size_t)b * C * H * W + h * W + w;
#pragma unroll
    for (int co = 0; co < C; co++) {
        const float f = acc[co] + db[co];
        op[co * H * W] = attp[co * H * W] * f + xr[co * H * W];
    }
}

// ---------------------------------------------------------------------------
extern "C" void kernel_launch(void* const* d_in, const int* in_sizes, int n_in,
                              void* d_out, int out_size, void* d_ws, size_t ws_size,
                              hipStream_t stream) {
    const float* x        = (const float*)d_in[0];
    const float* offset_w = (const float*)d_in[1];
    const float* offset_b = (const float*)d_in[2];
    const float* prelu_a  = (const float*)d_in[3];
    const float* deconv_w = (const float*)d_in[4];
    const float* deconv_b = (const float*)d_in[5];
    const float* conv_w   = (const float*)d_in[6];
    float* out = (float*)d_out;

    float* ws_offset = (float*)d_ws;                                  // B*18*H*W
    float* ws_atten  = ws_offset + (size_t)BB * KO * H * W;           // B*64*H*W

    conv_offset_atten_kernel<<<dim3(BB * H), dim3(128), 0, stream>>>(
        x, offset_w, offset_b, prelu_a, conv_w, ws_offset, ws_atten);

    deform_kernel<<<dim3((BB * H * W) / 256), dim3(256), 0, stream>>>(
        x, deconv_w, deconv_b, ws_offset, ws_atten, out);
}

// Round 2
// 748.319 us; speedup vs baseline: 1.0358x; 1.0358x over previous
//
#include <hip/hip_runtime.h>
#include <math.h>

#define BB 8
#define C 64
#define H 128
#define W 128
#define KO 18   // offset conv out channels (2*3*3)
#define NG 8    // groups
#define CPG 8   // channels per group
#define KK 9    // kernel taps
#define HW (H * W)

// ---------------------------------------------------------------------------
// Kernel 1: fused offset-conv (64->18, +PReLU) and atten-conv (64->64, raw
// logits). Thread-per-pixel, no LDS, no barriers. Weights are block-uniform
// -> scalar loads; latency hidden by ~4 waves/SIMD.
// ---------------------------------------------------------------------------
__global__ __launch_bounds__(256, 4)
void conv_offset_atten_kernel(const float* __restrict__ x,
                              const float* __restrict__ offw,   // [18][64][3][3]
                              const float* __restrict__ offb,   // [18]
                              const float* __restrict__ prelu_a,// [1]
                              const float* __restrict__ convw,  // [64][64][3][3]
                              float* __restrict__ ws_offset,    // [B][18][H][W]
                              float* __restrict__ ws_atten)     // [B][64][H][W] (logits)
{
    const int pid = blockIdx.x * 256 + threadIdx.x;
    const int w = pid & 127;
    const int h = (pid >> 7) & 127;
    const int b = pid >> 14;

    float accOff[KO];
    float accAtt[C];
#pragma unroll
    for (int i = 0; i < KO; i++) accOff[i] = offb[i];
#pragma unroll
    for (int i = 0; i < C; i++) accAtt[i] = 0.f;

    const float* xb = x + (size_t)b * C * HW + h * W + w;  // at (ci=0,h,w)

    const bool ym = (h > 0), yp = (h < H - 1);
    const bool xm = (w > 0), xp = (w < W - 1);
    const bool v[9] = { ym && xm, ym, ym && xp,
                        xm,       true, xp,
                        yp && xm, yp, yp && xp };
    const int  o[9] = { -W - 1, -W, -W + 1,
                        -1,      0,  1,
                         W - 1,  W,  W + 1 };

    for (int ci = 0; ci < C; ci++) {
        const float* xp0 = xb + ci * HW;
        float xv[9];
#pragma unroll
        for (int t = 0; t < 9; t++)
            xv[t] = v[t] ? xp0[o[t]] : 0.f;

#pragma unroll
        for (int co = 0; co < KO; co++) {
            const float* wp = offw + co * (C * 9) + ci * 9;
#pragma unroll
            for (int t = 0; t < 9; t++) accOff[co] = fmaf(xv[t], wp[t], accOff[co]);
        }
#pragma unroll
        for (int co = 0; co < C; co++) {
            const float* wp = convw + co * (C * 9) + ci * 9;
#pragma unroll
            for (int t = 0; t < 9; t++) accAtt[co] = fmaf(xv[t], wp[t], accAtt[co]);
        }
    }

    const float a = prelu_a[0];
    float* offo = ws_offset + (size_t)b * KO * HW + h * W + w;
#pragma unroll
    for (int co = 0; co < KO; co++) {
        float vv = accOff[co];
        offo[co * HW] = (vv >= 0.f) ? vv : a * vv;
    }
    float* atto = ws_atten + (size_t)b * C * HW + h * W + w;
#pragma unroll
    for (int co = 0; co < C; co++)
        atto[co * HW] = accAtt[co];
}

// ---------------------------------------------------------------------------
// Kernel 1b: in-place softmax over W. One wave per (b,co,h) row of 128.
// ---------------------------------------------------------------------------
__global__ __launch_bounds__(256)
void softmax_kernel(float* __restrict__ ws_atten)
{
    const int row = blockIdx.x * 4 + (threadIdx.x >> 6);  // 0 .. B*C*H-1
    const int lane = threadIdx.x & 63;
    float* p = ws_atten + (size_t)row * W;
    float v0 = p[lane];
    float v1 = p[lane + 64];
    float m = fmaxf(v0, v1);
#pragma unroll
    for (int off = 32; off > 0; off >>= 1)
        m = fmaxf(m, __shfl_xor(m, off, 64));
    float e0 = __expf(v0 - m);
    float e1 = __expf(v1 - m);
    float s = e0 + e1;
#pragma unroll
    for (int off = 32; off > 0; off >>= 1)
        s += __shfl_xor(s, off, 64);
    const float r = 1.f / s;
    p[lane] = e0 * r;
    p[lane + 64] = e1 * r;
}

// ---------------------------------------------------------------------------
// Kernel 2: deformable conv (groups=8) + bias, then out = atten*feat + x.
// ---------------------------------------------------------------------------
__global__ __launch_bounds__(256)
void deform_kernel(const float* __restrict__ x,
                   const float* __restrict__ dw,        // [64][8][3][3]
                   const float* __restrict__ db,        // [64]
                   const float* __restrict__ ws_offset, // [B][18][H][W]
                   const float* __restrict__ ws_atten,  // [B][64][H][W]
                   float* __restrict__ out)             // [B][64][H][W]
{
    __shared__ float wlds[9 * 512];   // [k][g][il][ol]

    for (int i = threadIdx.x; i < 9 * 512; i += 256) {
        int ol = i & 7;
        int il = (i >> 3) & 7;
        int g  = (i >> 6) & 7;
        int k  = i >> 9;
        wlds[i] = dw[((g * 8 + ol) * 8 + il) * 9 + k];
    }
    __syncthreads();

    const int pid = blockIdx.x * 256 + threadIdx.x;   // 0 .. B*H*W-1
    const int w = pid & 127;
    const int h = (pid >> 7) & 127;
    const int b = pid >> 14;

    const float* xb = x + (size_t)b * C * HW;
    const float* offp = ws_offset + (size_t)b * KO * HW + h * W + w;

    float acc[C];
#pragma unroll
    for (int i = 0; i < C; i++) acc[i] = 0.f;

    for (int k = 0; k < KK; k++) {
        const int ky = k / 3;
        const int kx = k - ky * 3;
        const float dy = offp[(2 * k) * HW];
        const float dx = offp[(2 * k + 1) * HW];
        const float ys = (float)(h - 1 + ky) + dy;
        const float xs = (float)(w - 1 + kx) + dx;
        const float y0f = floorf(ys), x0f = floorf(xs);
        const int y0 = (int)y0f, x0 = (int)x0f;
        const float fy = ys - y0f, fx = xs - x0f;
        float w00 = (1.f - fy) * (1.f - fx);
        float w01 = (1.f - fy) * fx;
        float w10 = fy * (1.f - fx);
        float w11 = fy * fx;
        const bool vy0 = (y0 >= 0) & (y0 < H);
        const bool vy1 = (y0 + 1 >= 0) & (y0 + 1 < H);
        const bool vx0 = (x0 >= 0) & (x0 < W);
        const bool vx1 = (x0 + 1 >= 0) & (x0 + 1 < W);
        w00 = (vy0 && vx0) ? w00 : 0.f;
        w01 = (vy0 && vx1) ? w01 : 0.f;
        w10 = (vy1 && vx0) ? w10 : 0.f;
        w11 = (vy1 && vx1) ? w11 : 0.f;
        const int yc0 = min(max(y0, 0), H - 1);
        const int yc1 = min(max(y0 + 1, 0), H - 1);
        const int xc0 = min(max(x0, 0), W - 1);
        const int xc1 = min(max(x0 + 1, 0), W - 1);
        const int o00 = yc0 * W + xc0, o01 = yc0 * W + xc1;
        const int o10 = yc1 * W + xc0, o11 = yc1 * W + xc1;

        const float* wk = wlds + k * 512;
#pragma unroll
        for (int g = 0; g < NG; g++) {
#pragma unroll
            for (int il = 0; il < CPG; il++) {
                const float* xp2 = xb + (g * CPG + il) * HW;
                const float p = w00 * xp2[o00] + w01 * xp2[o01]
                              + w10 * xp2[o10] + w11 * xp2[o11];
                const float* wp = wk + g * 64 + il * 8;
#pragma unroll
                for (int ol = 0; ol < CPG; ol++)
                    acc[g * CPG + ol] = fmaf(p, wp[ol], acc[g * CPG + ol]);
            }
        }
    }

    const float* attp = ws_atten + (size_t)b * C * HW + h * W + w;
    const float* xr = xb + h * W + w;
    float* op = out + (size_t)b * C * HW + h * W + w;
#pragma unroll
    for (int co = 0; co < C; co++) {
        const float f = acc[co] + db[co];
        op[co * HW] = attp[co * HW] * f + xr[co * HW];
    }
}

// ---------------------------------------------------------------------------
extern "C" void kernel_launch(void* const* d_in, const int* in_sizes, int n_in,
                              void* d_out, int out_size, void* d_ws, size_t ws_size,
                              hipStream_t stream) {
    const float* x        = (const float*)d_in[0];
    const float* offset_w = (const float*)d_in[1];
    const float* offset_b = (const float*)d_in[2];
    const float* prelu_a  = (const float*)d_in[3];
    const float* deconv_w = (const float*)d_in[4];
    const float* deconv_b = (const float*)d_in[5];
    const float* conv_w   = (const float*)d_in[6];
    float* out = (float*)d_out;

    float* ws_offset = (float*)d_ws;                            // B*18*H*W
    float* ws_atten  = ws_offset + (size_t)BB * KO * HW;        // B*64*H*W

    conv_offset_atten_kernel<<<dim3((BB * HW) / 256), dim3(256), 0, stream>>>(
        x, offset_w, offset_b, prelu_a, conv_w, ws_offset, ws_atten);

    softmax_kernel<<<dim3((BB * C * H) / 4), dim3(256), 0, stream>>>(ws_atten);

    deform_kernel<<<dim3((BB * HW) / 256), dim3(256), 0, stream>>>(
        x, deconv_w, deconv_b, ws_offset, ws_atten, out);
}

// Round 3
// 556.094 us; speedup vs baseline: 1.3939x; 1.3457x over previous
//
#include <hip/hip_runtime.h>
#include <math.h>

#define BB 8
#define C 64
#define H 128
#define W 128
#define KO 18   // offset conv out channels (2*3*3)
#define NG 8    // groups
#define CPG 8   // channels per group
#define KK 9    // kernel taps
#define HW (H * W)

// ---------------------------------------------------------------------------
// Kernel 0: transpose weights to ci-major for dense scalar loads.
//   attT[ci][co][t]  <- convw[co][ci][t]   (64x64x9)
//   offT[ci][co][t]  <- offw [co][ci][t]   (64x18x9)
// ---------------------------------------------------------------------------
__global__ __launch_bounds__(256)
void transpose_w_kernel(const float* __restrict__ offw,
                        const float* __restrict__ convw,
                        float* __restrict__ offT,
                        float* __restrict__ attT)
{
    const int i = blockIdx.x * 256 + threadIdx.x;
    if (i < C * C * KK) {
        int t = i % KK;
        int r = i / KK;
        int co = r % C;
        int ci = r / C;
        attT[ci * (C * KK) + co * KK + t] = convw[co * (C * KK) + ci * KK + t];
    }
    if (i < C * KO * KK) {
        int t = i % KK;
        int r = i / KK;
        int co = r % KO;
        int ci = r / KO;
        offT[ci * (KO * KK) + co * KK + t] = offw[co * (C * KK) + ci * KK + t];
    }
}

// ---------------------------------------------------------------------------
// Kernel A: offset conv (64->18) + PReLU. Block = one (b,h) row of 128 px.
// Thread = (pixel, half): 9 accumulators. half is wave-uniform.
// ---------------------------------------------------------------------------
__global__ __launch_bounds__(256, 8)
void offset_conv_kernel(const float* __restrict__ x,
                        const float* __restrict__ offT,   // [64][18][9]
                        const float* __restrict__ offb,   // [18]
                        const float* __restrict__ prelu_a,// [1]
                        float* __restrict__ ws_offset)    // [B][18][H][W]
{
    const int w = threadIdx.x & 127;
    const int half = __builtin_amdgcn_readfirstlane(threadIdx.x >> 7); // 0..1
    const int h = blockIdx.x & 127;
    const int b = blockIdx.x >> 7;

    float acc[9];
#pragma unroll
    for (int j = 0; j < 9; j++) acc[j] = offb[half * 9 + j];

    const float* xb = x + (size_t)b * C * HW + h * W + w;

    const bool ym = (h > 0), yp = (h < H - 1);
    const bool xm = (w > 0), xq = (w < W - 1);
    const bool v[9] = { ym && xm, ym, ym && xq,
                        xm,       true, xq,
                        yp && xm, yp, yp && xq };
    const int  o[9] = { -W - 1, -W, -W + 1,
                        -1,      0,  1,
                         W - 1,  W,  W + 1 };

    for (int ci = 0; ci < C; ci++) {
        const float* xp0 = xb + ci * HW;
        float xv[9];
#pragma unroll
        for (int t = 0; t < 9; t++) xv[t] = v[t] ? xp0[o[t]] : 0.f;

        const float* wp = offT + ci * (KO * KK) + half * 81;
#pragma unroll
        for (int j = 0; j < 9; j++)
#pragma unroll
            for (int t = 0; t < 9; t++)
                acc[j] = fmaf(xv[t], wp[j * 9 + t], acc[j]);
    }

    const float a = prelu_a[0];
    float* offo = ws_offset + ((size_t)b * KO + half * 9) * HW + h * W + w;
#pragma unroll
    for (int j = 0; j < 9; j++) {
        float vv = acc[j];
        offo[j * HW] = (vv >= 0.f) ? vv : a * vv;
    }
}

// ---------------------------------------------------------------------------
// Kernel B: atten conv (64->64), raw logits. Block = 64-px tile x 4 waves.
// Wave q computes co in [16q,16q+16): 16 accumulators/thread.
// ---------------------------------------------------------------------------
__global__ __launch_bounds__(256, 8)
void atten_conv_kernel(const float* __restrict__ x,
                       const float* __restrict__ attT,  // [64][64][9]
                       float* __restrict__ ws_atten)    // [B][64][H][W] logits
{
    const int lane = threadIdx.x & 63;
    const int q = __builtin_amdgcn_readfirstlane(threadIdx.x >> 6); // 0..3
    const int gid = blockIdx.x;
    const int tile = gid & 1;
    const int h = (gid >> 1) & 127;
    const int b = gid >> 8;
    const int w = tile * 64 + lane;

    float acc[16];
#pragma unroll
    for (int j = 0; j < 16; j++) acc[j] = 0.f;

    const float* xb = x + (size_t)b * C * HW + h * W + w;

    const bool ym = (h > 0), yp = (h < H - 1);
    const bool xm = (w > 0), xq = (w < W - 1);
    const bool v[9] = { ym && xm, ym, ym && xq,
                        xm,       true, xq,
                        yp && xm, yp, yp && xq };
    const int  o[9] = { -W - 1, -W, -W + 1,
                        -1,      0,  1,
                         W - 1,  W,  W + 1 };

    for (int ci = 0; ci < C; ci++) {
        const float* xp0 = xb + ci * HW;
        float xv[9];
#pragma unroll
        for (int t = 0; t < 9; t++) xv[t] = v[t] ? xp0[o[t]] : 0.f;

        const float* wp = attT + ci * (C * KK) + q * 144;
#pragma unroll
        for (int j = 0; j < 16; j++)
#pragma unroll
            for (int t = 0; t < 9; t++)
                acc[j] = fmaf(xv[t], wp[j * 9 + t], acc[j]);
    }

    float* atto = ws_atten + ((size_t)b * C + q * 16) * HW + h * W + w;
#pragma unroll
    for (int j = 0; j < 16; j++)
        atto[j * HW] = acc[j];
}

// ---------------------------------------------------------------------------
// Kernel 1b: in-place softmax over W. One wave per (b,co,h) row of 128.
// ---------------------------------------------------------------------------
__global__ __launch_bounds__(256)
void softmax_kernel(float* __restrict__ ws_atten)
{
    const int row = blockIdx.x * 4 + (threadIdx.x >> 6);  // 0 .. B*C*H-1
    const int lane = threadIdx.x & 63;
    float* p = ws_atten + (size_t)row * W;
    float v0 = p[lane];
    float v1 = p[lane + 64];
    float m = fmaxf(v0, v1);
#pragma unroll
    for (int off = 32; off > 0; off >>= 1)
        m = fmaxf(m, __shfl_xor(m, off, 64));
    float e0 = __expf(v0 - m);
    float e1 = __expf(v1 - m);
    float s = e0 + e1;
#pragma unroll
    for (int off = 32; off > 0; off >>= 1)
        s += __shfl_xor(s, off, 64);
    const float r = 1.f / s;
    p[lane] = e0 * r;
    p[lane + 64] = e1 * r;
}

// ---------------------------------------------------------------------------
// Kernel 2: deformable conv (groups=8) + bias, then out = atten*feat + x.
// ---------------------------------------------------------------------------
__global__ __launch_bounds__(256)
void deform_kernel(const float* __restrict__ x,
                   const float* __restrict__ dw,        // [64][8][3][3]
                   const float* __restrict__ db,        // [64]
                   const float* __restrict__ ws_offset, // [B][18][H][W]
                   const float* __restrict__ ws_atten,  // [B][64][H][W]
                   float* __restrict__ out)             // [B][64][H][W]
{
    __shared__ float wlds[9 * 512];   // [k][g][il][ol]

    for (int i = threadIdx.x; i < 9 * 512; i += 256) {
        int ol = i & 7;
        int il = (i >> 3) & 7;
        int g  = (i >> 6) & 7;
        int k  = i >> 9;
        wlds[i] = dw[((g * 8 + ol) * 8 + il) * 9 + k];
    }
    __syncthreads();

    const int pid = blockIdx.x * 256 + threadIdx.x;   // 0 .. B*H*W-1
    const int w = pid & 127;
    const int h = (pid >> 7) & 127;
    const int b = pid >> 14;

    const float* xb = x + (size_t)b * C * HW;
    const float* offp = ws_offset + (size_t)b * KO * HW + h * W + w;

    float acc[C];
#pragma unroll
    for (int i = 0; i < C; i++) acc[i] = 0.f;

    for (int k = 0; k < KK; k++) {
        const int ky = k / 3;
        const int kx = k - ky * 3;
        const float dy = offp[(2 * k) * HW];
        const float dx = offp[(2 * k + 1) * HW];
        const float ys = (float)(h - 1 + ky) + dy;
        const float xs = (float)(w - 1 + kx) + dx;
        const float y0f = floorf(ys), x0f = floorf(xs);
        const int y0 = (int)y0f, x0 = (int)x0f;
        const float fy = ys - y0f, fx = xs - x0f;
        float w00 = (1.f - fy) * (1.f - fx);
        float w01 = (1.f - fy) * fx;
        float w10 = fy * (1.f - fx);
        float w11 = fy * fx;
        const bool vy0 = (y0 >= 0) & (y0 < H);
        const bool vy1 = (y0 + 1 >= 0) & (y0 + 1 < H);
        const bool vx0 = (x0 >= 0) & (x0 < W);
        const bool vx1 = (x0 + 1 >= 0) & (x0 + 1 < W);
        w00 = (vy0 && vx0) ? w00 : 0.f;
        w01 = (vy0 && vx1) ? w01 : 0.f;
        w10 = (vy1 && vx0) ? w10 : 0.f;
        w11 = (vy1 && vx1) ? w11 : 0.f;
        const int yc0 = min(max(y0, 0), H - 1);
        const int yc1 = min(max(y0 + 1, 0), H - 1);
        const int xc0 = min(max(x0, 0), W - 1);
        const int xc1 = min(max(x0 + 1, 0), W - 1);
        const int o00 = yc0 * W + xc0, o01 = yc0 * W + xc1;
        const int o10 = yc1 * W + xc0, o11 = yc1 * W + xc1;

        const float* wk = wlds + k * 512;
#pragma unroll
        for (int g = 0; g < NG; g++) {
#pragma unroll
            for (int il = 0; il < CPG; il++) {
                const float* xp2 = xb + (g * CPG + il) * HW;
                const float p = w00 * xp2[o00] + w01 * xp2[o01]
                              + w10 * xp2[o10] + w11 * xp2[o11];
                const float* wp = wk + g * 64 + il * 8;
#pragma unroll
                for (int ol = 0; ol < CPG; ol++)
                    acc[g * CPG + ol] = fmaf(p, wp[ol], acc[g * CPG + ol]);
            }
        }
    }

    const float* attp = ws_atten + (size_t)b * C * HW + h * W + w;
    const float* xr = xb + h * W + w;
    float* op = out + (size_t)b * C * HW + h * W + w;
#pragma unroll
    for (int co = 0; co < C; co++) {
        const float f = acc[co] + db[co];
        op[co * HW] = attp[co * HW] * f + xr[co * HW];
    }
}

// ---------------------------------------------------------------------------
extern "C" void kernel_launch(void* const* d_in, const int* in_sizes, int n_in,
                              void* d_out, int out_size, void* d_ws, size_t ws_size,
                              hipStream_t stream) {
    const float* x        = (const float*)d_in[0];
    const float* offset_w = (const float*)d_in[1];
    const float* offset_b = (const float*)d_in[2];
    const float* prelu_a  = (const float*)d_in[3];
    const float* deconv_w = (const float*)d_in[4];
    const float* deconv_b = (const float*)d_in[5];
    const float* conv_w   = (const float*)d_in[6];
    float* out = (float*)d_out;

    float* ws_offset = (float*)d_ws;                            // B*18*H*W
    float* ws_atten  = ws_offset + (size_t)BB * KO * HW;        // B*64*H*W
    float* offT      = ws_atten + (size_t)BB * C * HW;          // 64*18*9
    float* attT      = offT + (size_t)C * KO * KK;              // 64*64*9

    transpose_w_kernel<<<dim3((C * C * KK + 255) / 256), dim3(256), 0, stream>>>(
        offset_w, conv_w, offT, attT);

    offset_conv_kernel<<<dim3(BB * H), dim3(256), 0, stream>>>(
        x, offT, offset_b, prelu_a, ws_offset);

    atten_conv_kernel<<<dim3(BB * H * 2), dim3(256), 0, stream>>>(
        x, attT, ws_atten);

    softmax_kernel<<<dim3((BB * C * H) / 4), dim3(256), 0, stream>>>(ws_atten);

    deform_kernel<<<dim3((BB * HW) / 256), dim3(256), 0, stream>>>(
        x, deconv_w, deconv_b, ws_offset, ws_atten, out);
}

// Round 4
// 380.149 us; speedup vs baseline: 2.0390x; 1.4628x over previous
//
#include <hip/hip_runtime.h>
#include <math.h>

#define BB 8
#define C 64
#define H 128
#define W 128
#define KO 18   // offset conv out channels (2*3*3)
#define NG 8    // groups
#define CPG 8   // channels per group
#define KK 9    // kernel taps
#define HW (H * W)
#define NCO 96  // padded co for MFMA conv (64 atten + 18 offset + 14 pad)
#define KTOT 576

typedef __bf16 bf16x8 __attribute__((ext_vector_type(8)));
typedef float f32x4 __attribute__((ext_vector_type(4)));
typedef unsigned int uint4v __attribute__((ext_vector_type(4)));

static __device__ __forceinline__ unsigned short f2bf(float f) {
    union { float f; unsigned u; } v; v.f = f;
    unsigned r = v.u + 0x7FFFu + ((v.u >> 16) & 1u);   // RNE
    return (unsigned short)(r >> 16);
}

static __device__ __forceinline__ bf16x8 load_bf8(const unsigned short* p) {
    uint4v u = *(const uint4v*)p;
    return __builtin_bit_cast(bf16x8, u);
}

// ---------------------------------------------------------------------------
// Prep A: x [B][C][H][W] fp32 -> x_cl [B][H][W][C] bf16 (channels-last).
// Block = 64 pixels x 4 ci-groups of 16.
// ---------------------------------------------------------------------------
__global__ __launch_bounds__(256)
void xcl_prep_kernel(const float* __restrict__ x, unsigned short* __restrict__ xcl)
{
    const int lane = threadIdx.x & 63;
    const int cg = threadIdx.x >> 6;          // 0..3
    const size_t P = (size_t)blockIdx.x * 64 + lane;   // global pixel id
    const int b = (int)(P >> 14);             // HW = 16384
    const int hw = (int)(P & 16383);

    union { unsigned short s[16]; uint4v v[2]; } u;
    const float* xp = x + ((size_t)b * C + cg * 16) * HW + hw;
#pragma unroll
    for (int i = 0; i < 16; i++)
        u.s[i] = f2bf(xp[i * HW]);

    uint4v* dst = (uint4v*)(xcl + P * 64 + cg * 16);
    dst[0] = u.v[0];
    dst[1] = u.v[1];
}

// ---------------------------------------------------------------------------
// Prep B: weights -> wT[96][576] bf16, k = tap*64 + ci.
//   co<64  : conv_w[co][ci][t]
//   64..81 : offset_w[co-64][ci][t]
//   else 0
// ---------------------------------------------------------------------------
__global__ __launch_bounds__(256)
void wt_prep_kernel(const float* __restrict__ convw,
                    const float* __restrict__ offw,
                    unsigned short* __restrict__ wT)
{
    const int i = blockIdx.x * 256 + threadIdx.x;
    if (i >= NCO * KTOT) return;
    const int k = i % KTOT;
    const int co = i / KTOT;
    const int t = k >> 6;
    const int ci = k & 63;
    float v = 0.f;
    if (co < 64)       v = convw[((size_t)co * C + ci) * KK + t];
    else if (co < 82)  v = offw[((size_t)(co - 64) * C + ci) * KK + t];
    wT[i] = f2bf(v);
}

// ---------------------------------------------------------------------------
// Fused conv via MFMA implicit GEMM: D[co][px] = sum_k wT[co][k] * X[k][px].
// Block = one (b,h) row (128 px), 4 waves; wave q covers px [32q, 32q+32)
// as 2 N-tiles of 16 px, x 6 M-tiles of 16 co. Epilogue: co<64 -> atten
// logits; co 64..81 -> offset with bias + PReLU.
// ---------------------------------------------------------------------------
__global__ __launch_bounds__(256)
void conv_mfma_kernel(const unsigned short* __restrict__ xcl,
                      const unsigned short* __restrict__ wT,
                      const float* __restrict__ offb,
                      const float* __restrict__ prelu_a,
                      float* __restrict__ ws_offset,   // [B][18][H][W]
                      float* __restrict__ ws_atten)    // [B][64][H][W] logits
{
    const int lane = threadIdx.x & 63;
    const int q = __builtin_amdgcn_readfirstlane(threadIdx.x >> 6);  // wave 0..3
    const int m = lane & 15;
    const int qq = lane >> 4;
    const int h = blockIdx.x & 127;
    const int b = blockIdx.x >> 7;

    f32x4 acc[2][6];
#pragma unroll
    for (int nt = 0; nt < 2; nt++)
#pragma unroll
        for (int mt = 0; mt < 6; mt++)
            acc[nt][mt] = (f32x4){0.f, 0.f, 0.f, 0.f};

    // weight fragment pointers: row co = mt*16+m, col chunk qq*8
    const unsigned short* wp[6];
#pragma unroll
    for (int mt = 0; mt < 6; mt++)
        wp[mt] = wT + (size_t)(mt * 16 + m) * KTOT + qq * 8;

    const int px0 = q * 32 + m;        // nt=0 pixel; nt=1 is +16

#pragma unroll
    for (int t = 0; t < KK; t++) {
        const int dy = t / 3 - 1;
        const int dx = t % 3 - 1;
        const int y = h + dy;
        const bool rowok = (y >= 0) && (y < H);
#pragma unroll
        for (int half = 0; half < 2; half++) {
            const int ks = t * 64 + half * 32;
            bf16x8 bfr[2];
#pragma unroll
            for (int nt = 0; nt < 2; nt++) {
                const int xx = px0 + nt * 16 + dx;
                const bool ok = rowok && (xx >= 0) && (xx < W);
                bf16x8 v = {};
                if (ok)
                    v = load_bf8(xcl + (((size_t)(b * H + y) * W + xx) * 64
                                        + half * 32 + qq * 8));
                bfr[nt] = v;
            }
#pragma unroll
            for (int mt = 0; mt < 6; mt++) {
                const bf16x8 afr = load_bf8(wp[mt] + ks);
                acc[0][mt] = __builtin_amdgcn_mfma_f32_16x16x32_bf16(
                    afr, bfr[0], acc[0][mt], 0, 0, 0);
                acc[1][mt] = __builtin_amdgcn_mfma_f32_16x16x32_bf16(
                    afr, bfr[1], acc[1][mt], 0, 0, 0);
            }
        }
    }

    // epilogue: D[row=co: qq*4+r][col=px: lane&15]
    const float a = prelu_a[0];
#pragma unroll
    for (int nt = 0; nt < 2; nt++) {
        const int wcol = px0 + nt * 16;
        // atten logits (co < 64)
#pragma unroll
        for (int mt = 0; mt < 4; mt++) {
            float* op = ws_atten + ((size_t)(b * 64 + mt * 16 + qq * 4)) * HW
                        + h * W + wcol;
#pragma unroll
            for (int r = 0; r < 4; r++)
                op[r * HW] = acc[nt][mt][r];
        }
        // offset channels 0..15 (mt=4)
#pragma unroll
        for (int r = 0; r < 4; r++) {
            const int j = qq * 4 + r;
            float v = acc[nt][4][r] + offb[j];
            v = (v >= 0.f) ? v : a * v;
            ws_offset[((size_t)(b * KO + j)) * HW + h * W + wcol] = v;
        }
        // offset channels 16..17 (mt=5)
#pragma unroll
        for (int r = 0; r < 4; r++) {
            const int j = 16 + qq * 4 + r;
            if (j < KO) {
                float v = acc[nt][5][r] + offb[j];
                v = (v >= 0.f) ? v : a * v;
                ws_offset[((size_t)(b * KO + j)) * HW + h * W + wcol] = v;
            }
        }
    }
}

// ---------------------------------------------------------------------------
// Softmax over W, in place. One wave per (b,co,h) row of 128.
// ---------------------------------------------------------------------------
__global__ __launch_bounds__(256)
void softmax_kernel(float* __restrict__ ws_atten)
{
    const int row = blockIdx.x * 4 + (threadIdx.x >> 6);
    const int lane = threadIdx.x & 63;
    float* p = ws_atten + (size_t)row * W;
    float v0 = p[lane];
    float v1 = p[lane + 64];
    float m = fmaxf(v0, v1);
#pragma unroll
    for (int off = 32; off > 0; off >>= 1)
        m = fmaxf(m, __shfl_xor(m, off, 64));
    float e0 = __expf(v0 - m);
    float e1 = __expf(v1 - m);
    float s = e0 + e1;
#pragma unroll
    for (int off = 32; off > 0; off >>= 1)
        s += __shfl_xor(s, off, 64);
    const float r = 1.f / s;
    p[lane] = e0 * r;
    p[lane + 64] = e1 * r;
}

// ---------------------------------------------------------------------------
// Deformable conv (groups=8) + bias, then out = atten*feat + x.
// ---------------------------------------------------------------------------
__global__ __launch_bounds__(256)
void deform_kernel(const float* __restrict__ x,
                   const float* __restrict__ dw,        // [64][8][3][3]
                   const float* __restrict__ db,        // [64]
                   const float* __restrict__ ws_offset, // [B][18][H][W]
                   const float* __restrict__ ws_atten,  // [B][64][H][W]
                   float* __restrict__ out)             // [B][64][H][W]
{
    __shared__ float wlds[9 * 512];   // [k][g][il][ol]

    for (int i = threadIdx.x; i < 9 * 512; i += 256) {
        int ol = i & 7;
        int il = (i >> 3) & 7;
        int g  = (i >> 6) & 7;
        int k  = i >> 9;
        wlds[i] = dw[((g * 8 + ol) * 8 + il) * 9 + k];
    }
    __syncthreads();

    const int pid = blockIdx.x * 256 + threadIdx.x;   // 0 .. B*H*W-1
    const int w = pid & 127;
    const int h = (pid >> 7) & 127;
    const int b = pid >> 14;

    const float* xb = x + (size_t)b * C * HW;
    const float* offp = ws_offset + (size_t)b * KO * HW + h * W + w;

    float acc[C];
#pragma unroll
    for (int i = 0; i < C; i++) acc[i] = 0.f;

    for (int k = 0; k < KK; k++) {
        const int ky = k / 3;
        const int kx = k - ky * 3;
        const float dy = offp[(2 * k) * HW];
        const float dx = offp[(2 * k + 1) * HW];
        const float ys = (float)(h - 1 + ky) + dy;
        const float xs = (float)(w - 1 + kx) + dx;
        const float y0f = floorf(ys), x0f = floorf(xs);
        const int y0 = (int)y0f, x0 = (int)x0f;
        const float fy = ys - y0f, fx = xs - x0f;
        float w00 = (1.f - fy) * (1.f - fx);
        float w01 = (1.f - fy) * fx;
        float w10 = fy * (1.f - fx);
        float w11 = fy * fx;
        const bool vy0 = (y0 >= 0) & (y0 < H);
        const bool vy1 = (y0 + 1 >= 0) & (y0 + 1 < H);
        const bool vx0 = (x0 >= 0) & (x0 < W);
        const bool vx1 = (x0 + 1 >= 0) & (x0 + 1 < W);
        w00 = (vy0 && vx0) ? w00 : 0.f;
        w01 = (vy0 && vx1) ? w01 : 0.f;
        w10 = (vy1 && vx0) ? w10 : 0.f;
        w11 = (vy1 && vx1) ? w11 : 0.f;
        const int yc0 = min(max(y0, 0), H - 1);
        const int yc1 = min(max(y0 + 1, 0), H - 1);
        const int xc0 = min(max(x0, 0), W - 1);
        const int xc1 = min(max(x0 + 1, 0), W - 1);
        const int o00 = yc0 * W + xc0, o01 = yc0 * W + xc1;
        const int o10 = yc1 * W + xc0, o11 = yc1 * W + xc1;

        const float* wk = wlds + k * 512;
#pragma unroll
        for (int g = 0; g < NG; g++) {
#pragma unroll
            for (int il = 0; il < CPG; il++) {
                const float* xp2 = xb + (g * CPG + il) * HW;
                const float p = w00 * xp2[o00] + w01 * xp2[o01]
                              + w10 * xp2[o10] + w11 * xp2[o11];
                const float* wp = wk + g * 64 + il * 8;
#pragma unroll
                for (int ol = 0; ol < CPG; ol++)
                    acc[g * CPG + ol] = fmaf(p, wp[ol], acc[g * CPG + ol]);
            }
        }
    }

    const float* attp = ws_atten + (size_t)b * C * HW + h * W + w;
    const float* xr = xb + h * W + w;
    float* op = out + (size_t)b * C * HW + h * W + w;
#pragma unroll
    for (int co = 0; co < C; co++) {
        const float f = acc[co] + db[co];
        op[co * HW] = attp[co * HW] * f + xr[co * HW];
    }
}

// ---------------------------------------------------------------------------
extern "C" void kernel_launch(void* const* d_in, const int* in_sizes, int n_in,
                              void* d_out, int out_size, void* d_ws, size_t ws_size,
                              hipStream_t stream) {
    const float* x        = (const float*)d_in[0];
    const float* offset_w = (const float*)d_in[1];
    const float* offset_b = (const float*)d_in[2];
    const float* prelu_a  = (const float*)d_in[3];
    const float* deconv_w = (const float*)d_in[4];
    const float* deconv_b = (const float*)d_in[5];
    const float* conv_w   = (const float*)d_in[6];
    float* out = (float*)d_out;

    float* ws_offset = (float*)d_ws;                            // B*18*HW f32
    float* ws_atten  = ws_offset + (size_t)BB * KO * HW;        // B*64*HW f32
    unsigned short* xcl = (unsigned short*)(ws_atten + (size_t)BB * C * HW);
    unsigned short* wT  = xcl + (size_t)BB * HW * C;            // 96*576 bf16

    xcl_prep_kernel<<<dim3((BB * HW) / 64), dim3(256), 0, stream>>>(x, xcl);
    wt_prep_kernel<<<dim3((NCO * KTOT + 255) / 256), dim3(256), 0, stream>>>(
        conv_w, offset_w, wT);

    conv_mfma_kernel<<<dim3(BB * H), dim3(256), 0, stream>>>(
        xcl, wT, offset_b, prelu_a, ws_offset, ws_atten);

    softmax_kernel<<<dim3((BB * C * H) / 4), dim3(256), 0, stream>>>(ws_atten);

    deform_kernel<<<dim3((BB * HW) / 256), dim3(256), 0, stream>>>(
        x, deconv_w, deconv_b, ws_offset, ws_atten, out);
}

// Round 5
// 299.305 us; speedup vs baseline: 2.5898x; 1.2701x over previous
//
#include <hip/hip_runtime.h>
#include <math.h>

#define BB 8
#define C 64
#define H 128
#define W 128
#define KO 18   // offset conv out channels (2*3*3)
#define NG 8    // groups
#define CPG 8   // channels per group
#define KK 9    // kernel taps
#define HW (H * W)
#define NCO 96  // padded co for MFMA conv (64 atten + 18 offset + 14 pad)
#define KTOT 576

typedef __bf16 bf16x8 __attribute__((ext_vector_type(8)));
typedef float f32x4 __attribute__((ext_vector_type(4)));
typedef unsigned int uint4v __attribute__((ext_vector_type(4)));

static __device__ __forceinline__ unsigned short f2bf(float f) {
    union { float f; unsigned u; } v; v.f = f;
    unsigned r = v.u + 0x7FFFu + ((v.u >> 16) & 1u);   // RNE
    return (unsigned short)(r >> 16);
}

static __device__ __forceinline__ bf16x8 load_bf8(const unsigned short* p) {
    uint4v u = *(const uint4v*)p;
    return __builtin_bit_cast(bf16x8, u);
}

static __device__ __forceinline__ float bflo(unsigned u) {
    union { unsigned u; float f; } v; v.u = u << 16; return v.f;
}
static __device__ __forceinline__ float bfhi(unsigned u) {
    union { unsigned u; float f; } v; v.u = u & 0xFFFF0000u; return v.f;
}

// ---------------------------------------------------------------------------
// Prep A: x [B][C][H][W] fp32 -> x_cl [B][H][W][C] bf16 (channels-last).
// ---------------------------------------------------------------------------
__global__ __launch_bounds__(256)
void xcl_prep_kernel(const float* __restrict__ x, unsigned short* __restrict__ xcl)
{
    const int lane = threadIdx.x & 63;
    const int cg = threadIdx.x >> 6;          // 0..3
    const size_t P = (size_t)blockIdx.x * 64 + lane;   // global pixel id
    const int b = (int)(P >> 14);             // HW = 16384
    const int hw = (int)(P & 16383);

    union { unsigned short s[16]; uint4v v[2]; } u;
    const float* xp = x + ((size_t)b * C + cg * 16) * HW + hw;
#pragma unroll
    for (int i = 0; i < 16; i++)
        u.s[i] = f2bf(xp[i * HW]);

    uint4v* dst = (uint4v*)(xcl + P * 64 + cg * 16);
    dst[0] = u.v[0];
    dst[1] = u.v[1];
}

// ---------------------------------------------------------------------------
// Prep B: weights -> wT[96][576] bf16, k = tap*64 + ci.
// ---------------------------------------------------------------------------
__global__ __launch_bounds__(256)
void wt_prep_kernel(const float* __restrict__ convw,
                    const float* __restrict__ offw,
                    unsigned short* __restrict__ wT)
{
    const int i = blockIdx.x * 256 + threadIdx.x;
    if (i >= NCO * KTOT) return;
    const int k = i % KTOT;
    const int co = i / KTOT;
    const int t = k >> 6;
    const int ci = k & 63;
    float v = 0.f;
    if (co < 64)       v = convw[((size_t)co * C + ci) * KK + t];
    else if (co < 82)  v = offw[((size_t)(co - 64) * C + ci) * KK + t];
    wT[i] = f2bf(v);
}

// ---------------------------------------------------------------------------
// Fused conv via MFMA implicit GEMM (64 atten logits + 18 offsets w/ PReLU).
// ---------------------------------------------------------------------------
__global__ __launch_bounds__(256)
void conv_mfma_kernel(const unsigned short* __restrict__ xcl,
                      const unsigned short* __restrict__ wT,
                      const float* __restrict__ offb,
                      const float* __restrict__ prelu_a,
                      float* __restrict__ ws_offset,   // [B][18][H][W]
                      float* __restrict__ ws_atten)    // [B][64][H][W] logits
{
    const int lane = threadIdx.x & 63;
    const int q = __builtin_amdgcn_readfirstlane(threadIdx.x >> 6);  // wave 0..3
    const int m = lane & 15;
    const int qq = lane >> 4;
    const int h = blockIdx.x & 127;
    const int b = blockIdx.x >> 7;

    f32x4 acc[2][6];
#pragma unroll
    for (int nt = 0; nt < 2; nt++)
#pragma unroll
        for (int mt = 0; mt < 6; mt++)
            acc[nt][mt] = (f32x4){0.f, 0.f, 0.f, 0.f};

    const unsigned short* wp[6];
#pragma unroll
    for (int mt = 0; mt < 6; mt++)
        wp[mt] = wT + (size_t)(mt * 16 + m) * KTOT + qq * 8;

    const int px0 = q * 32 + m;

#pragma unroll
    for (int t = 0; t < KK; t++) {
        const int dy = t / 3 - 1;
        const int dx = t % 3 - 1;
        const int y = h + dy;
        const bool rowok = (y >= 0) && (y < H);
#pragma unroll
        for (int half = 0; half < 2; half++) {
            const int ks = t * 64 + half * 32;
            bf16x8 bfr[2];
#pragma unroll
            for (int nt = 0; nt < 2; nt++) {
                const int xx = px0 + nt * 16 + dx;
                const bool ok = rowok && (xx >= 0) && (xx < W);
                bf16x8 v = {};
                if (ok)
                    v = load_bf8(xcl + (((size_t)(b * H + y) * W + xx) * 64
                                        + half * 32 + qq * 8));
                bfr[nt] = v;
            }
#pragma unroll
            for (int mt = 0; mt < 6; mt++) {
                const bf16x8 afr = load_bf8(wp[mt] + ks);
                acc[0][mt] = __builtin_amdgcn_mfma_f32_16x16x32_bf16(
                    afr, bfr[0], acc[0][mt], 0, 0, 0);
                acc[1][mt] = __builtin_amdgcn_mfma_f32_16x16x32_bf16(
                    afr, bfr[1], acc[1][mt], 0, 0, 0);
            }
        }
    }

    const float a = prelu_a[0];
#pragma unroll
    for (int nt = 0; nt < 2; nt++) {
        const int wcol = px0 + nt * 16;
#pragma unroll
        for (int mt = 0; mt < 4; mt++) {
            float* op = ws_atten + ((size_t)(b * 64 + mt * 16 + qq * 4)) * HW
                        + h * W + wcol;
#pragma unroll
            for (int r = 0; r < 4; r++)
                op[r * HW] = acc[nt][mt][r];
        }
#pragma unroll
        for (int r = 0; r < 4; r++) {
            const int j = qq * 4 + r;
            float v = acc[nt][4][r] + offb[j];
            v = (v >= 0.f) ? v : a * v;
            ws_offset[((size_t)(b * KO + j)) * HW + h * W + wcol] = v;
        }
#pragma unroll
        for (int r = 0; r < 4; r++) {
            const int j = 16 + qq * 4 + r;
            if (j < KO) {
                float v = acc[nt][5][r] + offb[j];
                v = (v >= 0.f) ? v : a * v;
                ws_offset[((size_t)(b * KO + j)) * HW + h * W + wcol] = v;
            }
        }
    }
}

// ---------------------------------------------------------------------------
// Softmax over W, in place. One wave per (b,co,h) row of 128.
// ---------------------------------------------------------------------------
__global__ __launch_bounds__(256)
void softmax_kernel(float* __restrict__ ws_atten)
{
    const int row = blockIdx.x * 4 + (threadIdx.x >> 6);
    const int lane = threadIdx.x & 63;
    float* p = ws_atten + (size_t)row * W;
    float v0 = p[lane];
    float v1 = p[lane + 64];
    float m = fmaxf(v0, v1);
#pragma unroll
    for (int off = 32; off > 0; off >>= 1)
        m = fmaxf(m, __shfl_xor(m, off, 64));
    float e0 = __expf(v0 - m);
    float e1 = __expf(v1 - m);
    float s = e0 + e1;
#pragma unroll
    for (int off = 32; off > 0; off >>= 1)
        s += __shfl_xor(s, off, 64);
    const float r = 1.f / s;
    p[lane] = e0 * r;
    p[lane + 64] = e1 * r;
}

// ---------------------------------------------------------------------------
// Deformable conv (groups=8) + bias, then out = atten*feat + x.
// Gather source: channels-last bf16 xcl -> each corner read is 128 B
// contiguous per lane. Block swizzle: b = blockIdx&7 so (assuming round-robin
// block->XCD) each XCD works one batch (2 MB xcl slab stays L2-resident).
// ---------------------------------------------------------------------------
__global__ __launch_bounds__(256)
void deform_kernel(const float* __restrict__ x,
                   const unsigned short* __restrict__ xcl, // [B][H][W][64] bf16
                   const float* __restrict__ dw,        // [64][8][3][3]
                   const float* __restrict__ db,        // [64]
                   const float* __restrict__ ws_offset, // [B][18][H][W]
                   const float* __restrict__ ws_atten,  // [B][64][H][W]
                   float* __restrict__ out)             // [B][64][H][W]
{
    __shared__ float wlds[9 * 512];   // [k][g][il][ol]

    for (int i = threadIdx.x; i < 9 * 512; i += 256) {
        int ol = i & 7;
        int il = (i >> 3) & 7;
        int g  = (i >> 6) & 7;
        int k  = i >> 9;
        wlds[i] = dw[((g * 8 + ol) * 8 + il) * 9 + k];
    }
    __syncthreads();

    // XCD-aware swizzle: batch = blockIdx & 7
    const int b = blockIdx.x & 7;
    const int rb = blockIdx.x >> 3;                  // 0..63 row-block
    const int pl = rb * 256 + threadIdx.x;           // 0..16383 pixel in batch
    const int w = pl & 127;
    const int h = pl >> 7;

    const unsigned short* xclb = xcl + (size_t)b * HW * 64;
    const float* offp = ws_offset + (size_t)b * KO * HW + h * W + w;

    float acc[C];
#pragma unroll
    for (int i = 0; i < C; i++) acc[i] = 0.f;

#pragma unroll
    for (int k = 0; k < KK; k++) {
        const int ky = k / 3;
        const int kx = k - ky * 3;
        const float dy = offp[(2 * k) * HW];
        const float dx = offp[(2 * k + 1) * HW];
        const float ys = (float)(h - 1 + ky) + dy;
        const float xs = (float)(w - 1 + kx) + dx;
        const float y0f = floorf(ys), x0f = floorf(xs);
        const int y0 = (int)y0f, x0 = (int)x0f;
        const float fy = ys - y0f, fx = xs - x0f;
        float w00 = (1.f - fy) * (1.f - fx);
        float w01 = (1.f - fy) * fx;
        float w10 = fy * (1.f - fx);
        float w11 = fy * fx;
        const bool vy0 = (y0 >= 0) & (y0 < H);
        const bool vy1 = (y0 + 1 >= 0) & (y0 + 1 < H);
        const bool vx0 = (x0 >= 0) & (x0 < W);
        const bool vx1 = (x0 + 1 >= 0) & (x0 + 1 < W);
        w00 = (vy0 && vx0) ? w00 : 0.f;
        w01 = (vy0 && vx1) ? w01 : 0.f;
        w10 = (vy1 && vx0) ? w10 : 0.f;
        w11 = (vy1 && vx1) ? w11 : 0.f;
        const int yc0 = min(max(y0, 0), H - 1);
        const int yc1 = min(max(y0 + 1, 0), H - 1);
        const int xc0 = min(max(x0, 0), W - 1);
        const int xc1 = min(max(x0 + 1, 0), W - 1);
        const unsigned short* p00 = xclb + (size_t)(yc0 * W + xc0) * 64;
        const unsigned short* p01 = xclb + (size_t)(yc0 * W + xc1) * 64;
        const unsigned short* p10 = xclb + (size_t)(yc1 * W + xc0) * 64;
        const unsigned short* p11 = xclb + (size_t)(yc1 * W + xc1) * 64;

        const float* wk = wlds + k * 512;
#pragma unroll
        for (int g = 0; g < NG; g++) {
            const uint4v c00 = *(const uint4v*)(p00 + g * 8);
            const uint4v c01 = *(const uint4v*)(p01 + g * 8);
            const uint4v c10 = *(const uint4v*)(p10 + g * 8);
            const uint4v c11 = *(const uint4v*)(p11 + g * 8);
            float p[8];
#pragma unroll
            for (int i = 0; i < 4; i++) {
                p[2 * i] = w00 * bflo(c00[i]) + w01 * bflo(c01[i])
                         + w10 * bflo(c10[i]) + w11 * bflo(c11[i]);
                p[2 * i + 1] = w00 * bfhi(c00[i]) + w01 * bfhi(c01[i])
                             + w10 * bfhi(c10[i]) + w11 * bfhi(c11[i]);
            }
            const float* wg = wk + g * 64;
#pragma unroll
            for (int il = 0; il < CPG; il++)
#pragma unroll
                for (int ol = 0; ol < CPG; ol++)
                    acc[g * CPG + ol] = fmaf(p[il], wg[il * 8 + ol],
                                             acc[g * CPG + ol]);
        }
    }

    const float* attp = ws_atten + (size_t)b * C * HW + h * W + w;
    const float* xr = x + (size_t)b * C * HW + h * W + w;
    float* op = out + (size_t)b * C * HW + h * W + w;
#pragma unroll
    for (int co = 0; co < C; co++) {
        const float f = acc[co] + db[co];
        op[co * HW] = attp[co * HW] * f + xr[co * HW];
    }
}

// ---------------------------------------------------------------------------
extern "C" void kernel_launch(void* const* d_in, const int* in_sizes, int n_in,
                              void* d_out, int out_size, void* d_ws, size_t ws_size,
                              hipStream_t stream) {
    const float* x        = (const float*)d_in[0];
    const float* offset_w = (const float*)d_in[1];
    const float* offset_b = (const float*)d_in[2];
    const float* prelu_a  = (const float*)d_in[3];
    const float* deconv_w = (const float*)d_in[4];
    const float* deconv_b = (const float*)d_in[5];
    const float* conv_w   = (const float*)d_in[6];
    float* out = (float*)d_out;

    float* ws_offset = (float*)d_ws;                            // B*18*HW f32
    float* ws_atten  = ws_offset + (size_t)BB * KO * HW;        // B*64*HW f32
    unsigned short* xcl = (unsigned short*)(ws_atten + (size_t)BB * C * HW);
    unsigned short* wT  = xcl + (size_t)BB * HW * C;            // 96*576 bf16

    xcl_prep_kernel<<<dim3((BB * HW) / 64), dim3(256), 0, stream>>>(x, xcl);
    wt_prep_kernel<<<dim3((NCO * KTOT + 255) / 256), dim3(256), 0, stream>>>(
        conv_w, offset_w, wT);

    conv_mfma_kernel<<<dim3(BB * H), dim3(256), 0, stream>>>(
        xcl, wT, offset_b, prelu_a, ws_offset, ws_atten);

    softmax_kernel<<<dim3((BB * C * H) / 4), dim3(256), 0, stream>>>(ws_atten);

    deform_kernel<<<dim3((BB * HW) / 256), dim3(256), 0, stream>>>(
        x, xcl, deconv_w, deconv_b, ws_offset, ws_atten, out);
}

// Round 6
// 271.934 us; speedup vs baseline: 2.8505x; 1.1007x over previous
//
#include <hip/hip_runtime.h>
#include <math.h>

#define BB 8
#define C 64
#define H 128
#define W 128
#define KO 18   // offset conv out channels (2*3*3)
#define NG 8    // groups
#define CPG 8   // channels per group
#define KK 9    // kernel taps
#define HW (H * W)
#define NCO 96  // padded co for MFMA conv (64 atten + 18 offset + 14 pad)
#define KTOT 576

typedef __bf16 bf16x8 __attribute__((ext_vector_type(8)));
typedef float f32x4 __attribute__((ext_vector_type(4)));
typedef unsigned int uint4v __attribute__((ext_vector_type(4)));

static __device__ __forceinline__ unsigned short f2bf(float f) {
    union { float f; unsigned u; } v; v.f = f;
    unsigned r = v.u + 0x7FFFu + ((v.u >> 16) & 1u);   // RNE
    return (unsigned short)(r >> 16);
}

static __device__ __forceinline__ bf16x8 load_bf8(const unsigned short* p) {
    uint4v u = *(const uint4v*)p;
    return __builtin_bit_cast(bf16x8, u);
}

static __device__ __forceinline__ float bflo(unsigned u) {
    union { unsigned u; float f; } v; v.u = u << 16; return v.f;
}
static __device__ __forceinline__ float bfhi(unsigned u) {
    union { unsigned u; float f; } v; v.u = u & 0xFFFF0000u; return v.f;
}

// ---------------------------------------------------------------------------
// Prep A: x [B][C][H][W] fp32 -> x_cl [B][H][W][C] bf16 (channels-last).
// ---------------------------------------------------------------------------
__global__ __launch_bounds__(256)
void xcl_prep_kernel(const float* __restrict__ x, unsigned short* __restrict__ xcl)
{
    const int lane = threadIdx.x & 63;
    const int cg = threadIdx.x >> 6;          // 0..3
    const size_t P = (size_t)blockIdx.x * 64 + lane;   // global pixel id
    const int b = (int)(P >> 14);             // HW = 16384
    const int hw = (int)(P & 16383);

    union { unsigned short s[16]; uint4v v[2]; } u;
    const float* xp = x + ((size_t)b * C + cg * 16) * HW + hw;
#pragma unroll
    for (int i = 0; i < 16; i++)
        u.s[i] = f2bf(xp[i * HW]);

    uint4v* dst = (uint4v*)(xcl + P * 64 + cg * 16);
    dst[0] = u.v[0];
    dst[1] = u.v[1];
}

// ---------------------------------------------------------------------------
// Prep B: weights -> wT[96][576] bf16, k = tap*64 + ci.
// ---------------------------------------------------------------------------
__global__ __launch_bounds__(256)
void wt_prep_kernel(const float* __restrict__ convw,
                    const float* __restrict__ offw,
                    unsigned short* __restrict__ wT)
{
    const int i = blockIdx.x * 256 + threadIdx.x;
    if (i >= NCO * KTOT) return;
    const int k = i % KTOT;
    const int co = i / KTOT;
    const int t = k >> 6;
    const int ci = k & 63;
    float v = 0.f;
    if (co < 64)       v = convw[((size_t)co * C + ci) * KK + t];
    else if (co < 82)  v = offw[((size_t)(co - 64) * C + ci) * KK + t];
    wT[i] = f2bf(v);
}

// ---------------------------------------------------------------------------
// Fused conv via MFMA implicit GEMM + in-block softmax over W.
// Block = one (b,h) row (128 px), 4 waves. Epilogue: co<64 -> softmax'd
// atten; co 64..81 -> offset with bias + PReLU.
// ---------------------------------------------------------------------------
__global__ __launch_bounds__(256)
void conv_mfma_kernel(const unsigned short* __restrict__ xcl,
                      const unsigned short* __restrict__ wT,
                      const float* __restrict__ offb,
                      const float* __restrict__ prelu_a,
                      float* __restrict__ ws_offset,   // [B][18][H][W]
                      float* __restrict__ ws_atten)    // [B][64][H][W] softmax
{
    __shared__ float smax[4][64];
    __shared__ float ssum[4][64];

    const int lane = threadIdx.x & 63;
    const int q = __builtin_amdgcn_readfirstlane(threadIdx.x >> 6);  // wave 0..3
    const int m = lane & 15;
    const int qq = lane >> 4;
    const int h = blockIdx.x & 127;
    const int b = blockIdx.x >> 7;

    f32x4 acc[2][6];
#pragma unroll
    for (int nt = 0; nt < 2; nt++)
#pragma unroll
        for (int mt = 0; mt < 6; mt++)
            acc[nt][mt] = (f32x4){0.f, 0.f, 0.f, 0.f};

    const unsigned short* wp[6];
#pragma unroll
    for (int mt = 0; mt < 6; mt++)
        wp[mt] = wT + (size_t)(mt * 16 + m) * KTOT + qq * 8;

    const int px0 = q * 32 + m;

#pragma unroll
    for (int t = 0; t < KK; t++) {
        const int dy = t / 3 - 1;
        const int dx = t % 3 - 1;
        const int y = h + dy;
        const bool rowok = (y >= 0) && (y < H);
#pragma unroll
        for (int half = 0; half < 2; half++) {
            const int ks = t * 64 + half * 32;
            bf16x8 bfr[2];
#pragma unroll
            for (int nt = 0; nt < 2; nt++) {
                const int xx = px0 + nt * 16 + dx;
                const bool ok = rowok && (xx >= 0) && (xx < W);
                bf16x8 v = {};
                if (ok)
                    v = load_bf8(xcl + (((size_t)(b * H + y) * W + xx) * 64
                                        + half * 32 + qq * 8));
                bfr[nt] = v;
            }
#pragma unroll
            for (int mt = 0; mt < 6; mt++) {
                const bf16x8 afr = load_bf8(wp[mt] + ks);
                acc[0][mt] = __builtin_amdgcn_mfma_f32_16x16x32_bf16(
                    afr, bfr[0], acc[0][mt], 0, 0, 0);
                acc[1][mt] = __builtin_amdgcn_mfma_f32_16x16x32_bf16(
                    afr, bfr[1], acc[1][mt], 0, 0, 0);
            }
        }
    }

    // ---- offsets (mt 4,5): bias + PReLU, store ----
    const float a = prelu_a[0];
#pragma unroll
    for (int nt = 0; nt < 2; nt++) {
        const int wcol = px0 + nt * 16;
#pragma unroll
        for (int r = 0; r < 4; r++) {
            const int j = qq * 4 + r;
            float v = acc[nt][4][r] + offb[j];
            v = (v >= 0.f) ? v : a * v;
            ws_offset[((size_t)(b * KO + j)) * HW + h * W + wcol] = v;
        }
#pragma unroll
        for (int r = 0; r < 4; r++) {
            const int j = 16 + qq * 4 + r;
            if (j < KO) {
                float v = acc[nt][5][r] + offb[j];
                v = (v >= 0.f) ? v : a * v;
                ws_offset[((size_t)(b * KO + j)) * HW + h * W + wcol] = v;
            }
        }
    }

    // ---- fused softmax over the 128-px row for co<64 (mt 0..3) ----
    // phase 1: row max
    float pm[4][4];
#pragma unroll
    for (int mt = 0; mt < 4; mt++)
#pragma unroll
        for (int r = 0; r < 4; r++)
            pm[mt][r] = fmaxf(acc[0][mt][r], acc[1][mt][r]);
#pragma unroll
    for (int off = 1; off < 16; off <<= 1)
#pragma unroll
        for (int mt = 0; mt < 4; mt++)
#pragma unroll
            for (int r = 0; r < 4; r++)
                pm[mt][r] = fmaxf(pm[mt][r], __shfl_xor(pm[mt][r], off, 64));
    if (m == 0) {
#pragma unroll
        for (int mt = 0; mt < 4; mt++)
#pragma unroll
            for (int r = 0; r < 4; r++)
                smax[q][mt * 16 + qq * 4 + r] = pm[mt][r];
    }
    __syncthreads();

    float gm[4][4], ps[4][4];
#pragma unroll
    for (int mt = 0; mt < 4; mt++)
#pragma unroll
        for (int r = 0; r < 4; r++) {
            const int co = mt * 16 + qq * 4 + r;
            gm[mt][r] = fmaxf(fmaxf(smax[0][co], smax[1][co]),
                              fmaxf(smax[2][co], smax[3][co]));
        }
    // phase 2: exp + row sum
#pragma unroll
    for (int mt = 0; mt < 4; mt++)
#pragma unroll
        for (int r = 0; r < 4; r++) {
            acc[0][mt][r] = __expf(acc[0][mt][r] - gm[mt][r]);
            acc[1][mt][r] = __expf(acc[1][mt][r] - gm[mt][r]);
            ps[mt][r] = acc[0][mt][r] + acc[1][mt][r];
        }
#pragma unroll
    for (int off = 1; off < 16; off <<= 1)
#pragma unroll
        for (int mt = 0; mt < 4; mt++)
#pragma unroll
            for (int r = 0; r < 4; r++)
                ps[mt][r] += __shfl_xor(ps[mt][r], off, 64);
    if (m == 0) {
#pragma unroll
        for (int mt = 0; mt < 4; mt++)
#pragma unroll
            for (int r = 0; r < 4; r++)
                ssum[q][mt * 16 + qq * 4 + r] = ps[mt][r];
    }
    __syncthreads();

#pragma unroll
    for (int mt = 0; mt < 4; mt++)
#pragma unroll
        for (int r = 0; r < 4; r++) {
            const int co = mt * 16 + qq * 4 + r;
            const float rinv = 1.f / (ssum[0][co] + ssum[1][co]
                                      + ssum[2][co] + ssum[3][co]);
            float* op = ws_atten + ((size_t)(b * 64 + co)) * HW + h * W;
            op[px0] = acc[0][mt][r] * rinv;
            op[px0 + 16] = acc[1][mt][r] * rinv;
        }
}

// ---------------------------------------------------------------------------
// Deformable conv (groups=8) + bias, then out = atten*feat + x.
// Thread = (pixel, channel-half): 4 groups, 32 accumulators. Block = one
// (b,h) row x 2 halves; grid = 1024 blocks -> 4 blocks/CU. XCD swizzle on b.
// ---------------------------------------------------------------------------
__global__ __launch_bounds__(256)
void deform_kernel(const float* __restrict__ x,
                   const unsigned short* __restrict__ xcl, // [B][H][W][64] bf16
                   const float* __restrict__ dw,        // [64][8][3][3]
                   const float* __restrict__ db,        // [64]
                   const float* __restrict__ ws_offset, // [B][18][H][W]
                   const float* __restrict__ ws_atten,  // [B][64][H][W]
                   float* __restrict__ out)             // [B][64][H][W]
{
    __shared__ float wlds[9 * 512];   // [k][g][il][ol]

    for (int i = threadIdx.x; i < 9 * 512; i += 256) {
        int ol = i & 7;
        int il = (i >> 3) & 7;
        int g  = (i >> 6) & 7;
        int k  = i >> 9;
        wlds[i] = dw[((g * 8 + ol) * 8 + il) * 9 + k];
    }
    __syncthreads();

    const int b = blockIdx.x & 7;                    // XCD-aware swizzle
    const int h = blockIdx.x >> 3;                   // 0..127 row
    const int w = threadIdx.x & 127;
    const int half = threadIdx.x >> 7;               // 0..1 (wave-uniform)
    const int g0 = half * 4;                         // first group
    const int co0 = half * 32;                       // first out channel

    const unsigned short* xclb = xcl + (size_t)b * HW * 64;
    const float* offp = ws_offset + (size_t)b * KO * HW + h * W + w;

    // prefetch all 18 offset values (independent loads)
    float dyv[9], dxv[9];
#pragma unroll
    for (int k = 0; k < KK; k++) {
        dyv[k] = offp[(2 * k) * HW];
        dxv[k] = offp[(2 * k + 1) * HW];
    }

    float acc[32];
#pragma unroll
    for (int i = 0; i < 32; i++) acc[i] = 0.f;

#pragma unroll
    for (int k = 0; k < KK; k++) {
        const int ky = k / 3;
        const int kx = k - ky * 3;
        const float ys = (float)(h - 1 + ky) + dyv[k];
        const float xs = (float)(w - 1 + kx) + dxv[k];
        const float y0f = floorf(ys), x0f = floorf(xs);
        const int y0 = (int)y0f, x0 = (int)x0f;
        const float fy = ys - y0f, fx = xs - x0f;
        float w00 = (1.f - fy) * (1.f - fx);
        float w01 = (1.f - fy) * fx;
        float w10 = fy * (1.f - fx);
        float w11 = fy * fx;
        const bool vy0 = (y0 >= 0) & (y0 < H);
        const bool vy1 = (y0 + 1 >= 0) & (y0 + 1 < H);
        const bool vx0 = (x0 >= 0) & (x0 < W);
        const bool vx1 = (x0 + 1 >= 0) & (x0 + 1 < W);
        w00 = (vy0 && vx0) ? w00 : 0.f;
        w01 = (vy0 && vx1) ? w01 : 0.f;
        w10 = (vy1 && vx0) ? w10 : 0.f;
        w11 = (vy1 && vx1) ? w11 : 0.f;
        const int yc0 = min(max(y0, 0), H - 1);
        const int yc1 = min(max(y0 + 1, 0), H - 1);
        const int xc0 = min(max(x0, 0), W - 1);
        const int xc1 = min(max(x0 + 1, 0), W - 1);
        const unsigned short* p00 = xclb + (size_t)(yc0 * W + xc0) * 64 + co0;
        const unsigned short* p01 = xclb + (size_t)(yc0 * W + xc1) * 64 + co0;
        const unsigned short* p10 = xclb + (size_t)(yc1 * W + xc0) * 64 + co0;
        const unsigned short* p11 = xclb + (size_t)(yc1 * W + xc1) * 64 + co0;

        const float* wk = wlds + k * 512 + g0 * 64;
#pragma unroll
        for (int g = 0; g < 4; g++) {
            const uint4v c00 = *(const uint4v*)(p00 + g * 8);
            const uint4v c01 = *(const uint4v*)(p01 + g * 8);
            const uint4v c10 = *(const uint4v*)(p10 + g * 8);
            const uint4v c11 = *(const uint4v*)(p11 + g * 8);
            float p[8];
#pragma unroll
            for (int i = 0; i < 4; i++) {
                p[2 * i] = w00 * bflo(c00[i]) + w01 * bflo(c01[i])
                         + w10 * bflo(c10[i]) + w11 * bflo(c11[i]);
                p[2 * i + 1] = w00 * bfhi(c00[i]) + w01 * bfhi(c01[i])
                             + w10 * bfhi(c10[i]) + w11 * bfhi(c11[i]);
            }
            const float* wg = wk + g * 64;
#pragma unroll
            for (int il = 0; il < CPG; il++)
#pragma unroll
                for (int ol = 0; ol < CPG; ol++)
                    acc[g * CPG + ol] = fmaf(p[il], wg[il * 8 + ol],
                                             acc[g * CPG + ol]);
        }
    }

    const float* attp = ws_atten + ((size_t)b * C + co0) * HW + h * W + w;
    const float* xr = x + ((size_t)b * C + co0) * HW + h * W + w;
    float* op = out + ((size_t)b * C + co0) * HW + h * W + w;
#pragma unroll
    for (int j = 0; j < 32; j++) {
        const float f = acc[j] + db[co0 + j];
        op[j * HW] = attp[j * HW] * f + xr[j * HW];
    }
}

// ---------------------------------------------------------------------------
extern "C" void kernel_launch(void* const* d_in, const int* in_sizes, int n_in,
                              void* d_out, int out_size, void* d_ws, size_t ws_size,
                              hipStream_t stream) {
    const float* x        = (const float*)d_in[0];
    const float* offset_w = (const float*)d_in[1];
    const float* offset_b = (const float*)d_in[2];
    const float* prelu_a  = (const float*)d_in[3];
    const float* deconv_w = (const float*)d_in[4];
    const float* deconv_b = (const float*)d_in[5];
    const float* conv_w   = (const float*)d_in[6];
    float* out = (float*)d_out;

    float* ws_offset = (float*)d_ws;                            // B*18*HW f32
    float* ws_atten  = ws_offset + (size_t)BB * KO * HW;        // B*64*HW f32
    unsigned short* xcl = (unsigned short*)(ws_atten + (size_t)BB * C * HW);
    unsigned short* wT  = xcl + (size_t)BB * HW * C;            // 96*576 bf16

    xcl_prep_kernel<<<dim3((BB * HW) / 64), dim3(256), 0, stream>>>(x, xcl);
    wt_prep_kernel<<<dim3((NCO * KTOT + 255) / 256), dim3(256), 0, stream>>>(
        conv_w, offset_w, wT);

    conv_mfma_kernel<<<dim3(BB * H), dim3(256), 0, stream>>>(
        xcl, wT, offset_b, prelu_a, ws_offset, ws_atten);

    deform_kernel<<<dim3(BB * H), dim3(256), 0, stream>>>(
        x, xcl, deconv_w, deconv_b, ws_offset, ws_atten, out);
}